// Round 1
// baseline (519.442 us; speedup 1.0000x reference)
//
#include <hip/hip_runtime.h>

typedef _Float16 f16x8 __attribute__((ext_vector_type(8)));
typedef _Float16 f16x2 __attribute__((ext_vector_type(2)));
typedef float f32x4 __attribute__((ext_vector_type(4)));

#define SLOT_DW 2048              // dwords per (b,t) slot: kA writes 1408 dw (f16 band), kB overwrites with 2048 dw frame
#define WT_BYTE_OFF 134217728     // 16384*2048*4 ; Wt (f16) after slots
#define PHYS(i) ((i) + ((i) >> 5))   // LDS pad swizzle for FFT buffers

// ---- precomputed block-invariant tables (device globals, filled by k_tab) ----
__device__ float4 d_TW4[5][256];   // per (stage, tid): cos/sin of ang, 2*ang
__device__ float2 d_TW2[5][256];   // per (stage, tid): cos/sin of 3*ang
__device__ float2 d_PK[513];       // pack twiddle: (cos, sin)(k*pi/1024)
__device__ float4 d_WN4[512];      // window*1/N for samples 4j..4j+3
__device__ float4 d_GL[1025];      // gather LUT: (meta, inv, bias_r*inv, bias_i*inv)

__device__ __forceinline__ void async_copy16(const void* g, void* l) {
  __builtin_amdgcn_global_load_lds((const __attribute__((address_space(1))) void*)g,
                                   (__attribute__((address_space(3))) void*)l, 16, 0, 0);
}

// ---------------- K0: transpose+scale W -> Wt[n][o][d] (f16, x4096) ----------------
// 88 blocks: band n = bx>>2, d-quarter dq = bx&3 (32 d-rows each)
__global__ __launch_bounds__(256) void k_init(const float* __restrict__ W,
                                              _Float16* __restrict__ Wt) {
  int n = blockIdx.x >> 2, dq = blockIdx.x & 3;
  int tid = threadIdx.x;
  __shared__ _Float16 L[32 * 130];
  const float* Wn = W + (size_t)n * 16384 + dq * 32 * 128;
  for (int el = tid; el < 4096; el += 256) {
    int dl = el >> 7, o = el & 127;
    L[dl * 130 + o] = (_Float16)(Wn[el] * 4096.0f);
  }
  __syncthreads();
  _Float16* Wtn = Wt + (size_t)n * 16384 + dq * 32;
  for (int el = tid; el < 4096; el += 256) {
    int o = el >> 5, dl = el & 31;
    Wtn[o * 128 + dl] = L[dl * 130 + o];
  }
}

// ---------------- K0b: fill block-invariant LUTs (trig + gather descriptors) ----------------
// items: 1280 FFT twiddles | 1025 gather | 513 pack | 512 window  => 3330, 14 blocks
__global__ __launch_bounds__(256) void k_tab(const float* __restrict__ bias) {
  int i = blockIdx.x * 256 + threadIdx.x;
  if (i < 1280) {
    int st = i >> 8, tid = i & 255;
    int s = 2 * st;
    int qm = (tid >> s) << s;   // q * m
    float ang = (float)qm * 6.135923151542565e-3f;   // 2*pi/1024
    d_TW4[st][tid] = make_float4(cosf(ang), sinf(ang), cosf(2.0f * ang), sinf(2.0f * ang));
    d_TW2[st][tid] = make_float2(cosf(3.0f * ang), sinf(3.0f * ang));
  } else if (i < 1280 + 1025) {
    int f = i - 1280;
    int nhi = f / 48; if (nhi > 20) nhi = 20;
    int nlo = (f >= 16) ? (f - 16) / 48 : 0;
    int cnt = nhi - nlo + 1;              // regular-band count (0 only for f==1024)
    int has21 = (f >= 961) ? 1 : 0;
    int base = 32 * nlo + 2 * f;          // n*128 + 2*(f-48n) == 32n + 2f
    float bsr = 0.f, bsi = 0.f;
    for (int n = nlo; n <= nhi; n++) {
      bsr += bias[32 * n + 2 * f];
      bsi += bias[32 * n + 2 * f + 1];
    }
    if (has21) { bsr += bias[766 + 2 * f]; bsi += bias[766 + 2 * f + 1]; }
    int wgt = cnt + has21;
    if (cnt == 0) { base = 766 + 2 * f; cnt = 1; has21 = 0; }   // f==1024: band21 only
    float inv = 1.0f / (float)wgt;
    int meta = base | (cnt << 16) | (has21 << 20);
    d_GL[f] = make_float4(__int_as_float(meta), inv, bsr * inv, bsi * inv);
  } else if (i < 1280 + 1025 + 513) {
    int k = i - 2305;
    float ang = (float)k * 3.0679615757712823e-3f;   // pi/1024
    d_PK[k] = make_float2(cosf(ang), sinf(ang));
  } else if (i < 1280 + 1025 + 513 + 512) {
    int j = i - 2818;   // covers samples 4j..4j+3
    const float inv_n = 1.0f / 2048.0f;
    float4 w;
    w.x = inv_n * 0.5f * (1.0f - cosf((float)(4 * j)     * 3.0679615757712823e-3f));
    w.y = inv_n * 0.5f * (1.0f - cosf((float)(4 * j + 1) * 3.0679615757712823e-3f));
    w.z = inv_n * 0.5f * (1.0f - cosf((float)(4 * j + 2) * 3.0679615757712823e-3f));
    w.w = inv_n * 0.5f * (1.0f - cosf((float)(4 * j + 3) * 3.0679615757712823e-3f));
    d_WN4[j] = w;
  }
}

// ---------------- KA: per-band GEMM, async LDS staging + reg-resident B ----------------
// block: 64 rows x 128 cols, one band. Wave w owns col-tiles {2w,2w+1} over 4 row-tiles.
__global__ __launch_bounds__(256) void kA(const float* __restrict__ z,
                                          const _Float16* __restrict__ Wt,
                                          _Float16* __restrict__ band) {
  int mt = blockIdx.x;   // 0..255
  int n  = blockIdx.y;   // 0..21
  int r0 = mt * 64;
  __shared__ __align__(16) char smem[33280];   // 32 row-pairs x 1040B (fp32 z), aliased by epilogue Cs
  int tid = threadIdx.x;
  int lane = tid & 63, wave = tid >> 6;
  int l16 = lane & 15, quad = lane >> 4;

  // preload all B fragments (band-n weights; L2-hot across 256 blocks) -> 32 VGPRs
  const _Float16* Wn = Wt + (size_t)n * 16384;
  f16x8 bfrag[8];
#pragma unroll
  for (int kb = 0; kb < 4; kb++) {
    int ko = kb * 32 + quad * 8;
    bfrag[2 * kb]     = *(const f16x8*)(Wn + (wave * 32 + l16) * 128 + ko);
    bfrag[2 * kb + 1] = *(const f16x8*)(Wn + (wave * 32 + 16 + l16) * 128 + ko);
  }

  // async-stage 64 z rows (band n, fp32). Pair p -> LDS [p*1040, p*1040+1024).
  // One issue per wave: lanes 0-31 = row 2p (16B chunks), lanes 32-63 = row 2p+1.
  {
    int col16 = lane & 31;
    int rowh  = lane >> 5;
#pragma unroll
    for (int it = 0; it < 8; it++) {
      int pr = wave * 8 + it;
      const float* g = z + ((size_t)(r0 + 2 * pr + rowh) * 22 + n) * 128 + col16 * 4;
      async_copy16(g, smem + pr * 1040);
    }
  }
  __syncthreads();

  f32x4 acc[2][4];
#pragma unroll
  for (int c = 0; c < 2; c++)
#pragma unroll
    for (int rt = 0; rt < 4; rt++) acc[c][rt] = (f32x4){0.f, 0.f, 0.f, 0.f};

#pragma unroll
  for (int kb = 0; kb < 4; kb++) {
#pragma unroll
    for (int rt = 0; rt < 4; rt++) {
      int row = rt * 16 + l16;
      const float* ap = (const float*)(smem + (row >> 1) * 1040 + (row & 1) * 512) + kb * 32 + quad * 8;
      float4 v0 = *(const float4*)ap;
      float4 v1 = *(const float4*)(ap + 4);
      f16x8 a;
      a[0] = (_Float16)v0.x; a[1] = (_Float16)v0.y; a[2] = (_Float16)v0.z; a[3] = (_Float16)v0.w;
      a[4] = (_Float16)v1.x; a[5] = (_Float16)v1.y; a[6] = (_Float16)v1.z; a[7] = (_Float16)v1.w;
      acc[0][rt] = __builtin_amdgcn_mfma_f32_16x16x32_f16(a, bfrag[2 * kb],     acc[0][rt], 0, 0, 0);
      acc[1][rt] = __builtin_amdgcn_mfma_f32_16x16x32_f16(a, bfrag[2 * kb + 1], acc[1][rt], 0, 0, 0);
    }
  }
  __syncthreads();   // zs dead; reuse smem as Cs staging

  _Float16* Cs = (_Float16*)smem;
  const float inv_scale = 1.0f / 4096.0f;
#pragma unroll
  for (int c = 0; c < 2; c++) {
    int col = (wave * 2 + c) * 16 + l16;
#pragma unroll
    for (int rt = 0; rt < 4; rt++) {
#pragma unroll
      for (int reg = 0; reg < 4; reg++) {
        int row = rt * 16 + quad * 4 + reg;
        Cs[row * 136 + col] = (_Float16)(acc[c][rt][reg] * inv_scale);
      }
    }
  }
  __syncthreads();
  int row = tid >> 2;
  int c4 = (tid & 3) * 32;
  const _Float16* srcl = &Cs[row * 136 + c4];
  _Float16* dst = band + (size_t)(r0 + row) * (SLOT_DW * 2) + n * 128 + c4;
  f16x8 v0 = *(const f16x8*)(srcl);
  f16x8 v1 = *(const f16x8*)(srcl + 8);
  f16x8 v2 = *(const f16x8*)(srcl + 16);
  f16x8 v3 = *(const f16x8*)(srcl + 24);
  *(f16x8*)(dst)      = v0;
  *(f16x8*)(dst + 8)  = v1;
  *(f16x8*)(dst + 16) = v2;
  *(f16x8*)(dst + 24) = v3;
}

// ---------------- KB: mask gather + pack (conjugate pairs) + radix-4 Stockham IFFT + window ----------------
// All trig / bias / weight terms come from LUTs (block-invariant, L2-hot).
__global__ __launch_bounds__(256) void kB(const float* __restrict__ mix,
                                          float* __restrict__ ws) {
  int r = blockIdx.x;           // 0..16383
  int b = r >> 11, t = r & 2047;
  __shared__ __align__(16) float2 bufA[1056];   // swizzled: PHYS(i)=i+(i>>5)
  __shared__ __align__(16) float2 bufB[1056];
  int tid = threadIdx.x;

  const _Float16* bandg = (const _Float16*)(ws + (size_t)r * SLOT_DW);
  const float* mixr = mix + ((size_t)(b * 2) * 2048 + t) * 1025;
  const float* mixi = mix + ((size_t)(b * 2 + 1) * 2048 + t) * 1025;

  // ---- fused mask gather + complex-mul + real-pack (pairs k, 1024-k) ----
  for (int k = tid; k <= 512; k += 256) {
    float2 X[2];
#pragma unroll
    for (int side = 0; side < 2; side++) {
      int f = side ? (1024 - k) : k;
      float4 ge = d_GL[f];
      int meta = __float_as_int(ge.x);
      const _Float16* bp = bandg + (meta & 0xFFFF);
      f16x2 v0 = *(const f16x2*)bp;
      float sr = (float)v0[0], si = (float)v0[1];
      int cnt = (meta >> 16) & 15;
      if (cnt > 1) { f16x2 v = *(const f16x2*)(bp + 32); sr += (float)v[0]; si += (float)v[1]; }
      if (meta >> 20) { f16x2 v = *(const f16x2*)(bandg + 766 + 2 * f); sr += (float)v[0]; si += (float)v[1]; }
      float mr = sr * ge.y + ge.z;
      float mi = si * ge.y + ge.w;
      float xr = mixr[f], xi = mixi[f];
      float outr = mr * xr - mi * xi;
      float outi = mr * xi + mi * mr * 0.0f + mi * xr;   // keep simple: recomputed below
      outi = mr * xi + mi * xr;
      if ((f & 1023) == 0) outi = 0.0f;   // c2r ignores Im at DC/Nyquist
      X[side] = make_float2(outr, outi);
      if (k == 512) { X[1] = X[0]; break; }   // self-paired center
    }
    float Ar = X[0].x + X[1].x, Ai = X[0].y - X[1].y;
    float Br = X[0].x - X[1].x, Bi = X[0].y + X[1].y;
    float2 pk = d_PK[k];
    float s1 = pk.x * Bi + pk.y * Br;
    float s2 = pk.x * Br - pk.y * Bi;
    bufA[PHYS(k & 1023)] = make_float2(Ar - s1, Ai + s2);
    if (k > 0 && k < 512) bufA[PHYS(1024 - k)] = make_float2(Ar + s1, -Ai + s2);
  }

  // ---- radix-4 Stockham inverse FFT (5 double-stages, LUT twiddles, unnormalized) ----
  float2* src = bufA;
  float2* dst = bufB;
#pragma unroll
  for (int st = 0; st < 5; st++) {
    const int s = 2 * st;
    const int m = 1 << s;
    __syncthreads();
    float4 w12 = d_TW4[st][tid];
    float2 w3t = d_TW2[st][tid];
    int q = tid >> s, rr = tid & (m - 1);
    float2 x0 = src[PHYS(tid)];
    float2 x1 = src[PHYS(tid + 256)];
    float2 x2 = src[PHYS(tid + 512)];
    float2 x3 = src[PHYS(tid + 768)];
    float wc1 = w12.x, ws1 = w12.y, wc2 = w12.z, ws2 = w12.w;
    float wc3 = w3t.x, ws3 = w3t.y;
    float tAr = x0.x + x2.x, tAi = x0.y + x2.y;
    float tBr = x0.x - x2.x, tBi = x0.y - x2.y;
    float tCr = x1.x + x3.x, tCi = x1.y + x3.y;
    float tDr = x1.x - x3.x, tDi = x1.y - x3.y;
    int base = 4 * q * m + rr;
    dst[PHYS(base)] = make_float2(tAr + tCr, tAi + tCi);
    float pr = tBr - tDi, pi = tBi + tDr;                  // tB + i*tD
    dst[PHYS(base + m)] = make_float2(wc1 * pr - ws1 * pi, wc1 * pi + ws1 * pr);
    float qr = tAr - tCr, qi = tAi - tCi;
    dst[PHYS(base + 2 * m)] = make_float2(wc2 * qr - ws2 * qi, wc2 * qi + ws2 * qr);
    float rr2 = tBr + tDi, ri2 = tBi - tDr;                // tB - i*tD
    dst[PHYS(base + 3 * m)] = make_float2(wc3 * rr2 - ws3 * ri2, wc3 * ri2 + ws3 * rr2);
    float2* tmp = src; src = dst; dst = tmp;
  }
  __syncthreads();

  // ---- window + store frame, vectorized: 4 samples / thread / iter ----
  float4* slot4 = (float4*)(ws + (size_t)r * SLOT_DW);
#pragma unroll
  for (int it = 0; it < 2; it++) {
    int i = tid + 256 * it;           // sample group 4i..4i+3
    float2 g0 = src[PHYS(2 * i)];
    float2 g1 = src[PHYS(2 * i + 1)];
    float4 w = d_WN4[i];
    slot4[i] = make_float4(g0.x * w.x, g0.y * w.y, g1.x * w.z, g1.y * w.w);
  }
}

// ---------------- KC: overlap-add gather + env normalize + crop ----------------
__global__ __launch_bounds__(256) void kC(const float* __restrict__ ws,
                                          float* __restrict__ out) {
  int b = blockIdx.y;
  int p = blockIdx.x * 256 + threadIdx.x;   // 0..1048063 (exact grid)
  int q = p + 1024;
  int t0 = (q - 1536) >> 9; if (t0 < 0) t0 = 0;
  int t1 = q >> 9;          if (t1 > 2047) t1 = 2047;
  float sum = 0.f;
  for (int t = t0; t <= t1; t++) {
    int i = q - (t << 9);
    sum += ws[(size_t)(b * 2048 + t) * SLOT_DW + i];    // frames already windowed
  }
  float env;
  if (t1 - t0 == 3) {
    env = 1.5f;  // Hann, hop=WIN/4: interior sum of win^2 is exactly 1.5
  } else {
    env = 0.f;
    for (int t = t0; t <= t1; t++) {
      int i = q - (t << 9);
      float c = __cosf((float)i * 3.0679615757712823e-3f);
      float win = 0.5f * (1.0f - c);
      env += win * win;
    }
  }
  out[(size_t)b * 1048064 + p] = sum / (env > 1e-11f ? env : 1.0f);
}

extern "C" void kernel_launch(void* const* d_in, const int* in_sizes, int n_in,
                              void* d_out, int out_size, void* d_ws, size_t ws_size,
                              hipStream_t stream) {
  const float* z    = (const float*)d_in[0];
  const float* mix  = (const float*)d_in[1];
  const float* W    = (const float*)d_in[2];
  const float* bias = (const float*)d_in[3];
  float* out = (float*)d_out;
  _Float16* Wt = (_Float16*)((char*)d_ws + WT_BYTE_OFF);

  k_init<<<88, 256, 0, stream>>>(W, Wt);
  k_tab<<<14, 256, 0, stream>>>(bias);
  kA<<<dim3(256, 22), 256, 0, stream>>>(z, Wt, (_Float16*)d_ws);
  kB<<<16384, 256, 0, stream>>>(mix, (float*)d_ws);
  kC<<<dim3(4094, 8), 256, 0, stream>>>((const float*)d_ws, out);
}

// Round 2
// 489.267 us; speedup vs baseline: 1.0617x; 1.0617x over previous
//
#include <hip/hip_runtime.h>

typedef _Float16 f16x8 __attribute__((ext_vector_type(8)));
typedef _Float16 f16x2 __attribute__((ext_vector_type(2)));
typedef float f32x4 __attribute__((ext_vector_type(4)));

#define SLOT_DW 2048              // dwords per (b,t) slot: kA writes 1408 dw (f16 band), kB overwrites with 2048 dw frame
#define WT_BYTE_OFF 134217728     // 16384*2048*4 ; Wt (f16) after slots
#define PHYS(i) ((i) + ((i) >> 5))   // LDS pad swizzle for FFT buffers

// ---- precomputed block-invariant tables (device globals, filled by k_tab) ----
__device__ float4 d_TW4[5][256];   // per (stage, tid): cos/sin of ang, 2*ang
__device__ float2 d_TW2[5][256];   // per (stage, tid): cos/sin of 3*ang
__device__ float2 d_PK[513];       // pack twiddle: (cos, sin)(k*pi/1024)
__device__ float4 d_WN4[512];      // window*1/N for samples 4j..4j+3
__device__ float4 d_GL[1025];      // gather LUT: (unused, inv, bias_r*inv, bias_i*inv)

__device__ __forceinline__ void async_copy16(const void* g, void* l) {
  __builtin_amdgcn_global_load_lds((const __attribute__((address_space(1))) void*)g,
                                   (__attribute__((address_space(3))) void*)l, 16, 0, 0);
}

// ---------------- K0: transpose+scale W -> Wt[n][o][d] (f16, x4096) ----------------
__global__ __launch_bounds__(256) void k_init(const float* __restrict__ W,
                                              _Float16* __restrict__ Wt) {
  int n = blockIdx.x >> 2, dq = blockIdx.x & 3;
  int tid = threadIdx.x;
  __shared__ _Float16 L[32 * 130];
  const float* Wn = W + (size_t)n * 16384 + dq * 32 * 128;
  for (int el = tid; el < 4096; el += 256) {
    int dl = el >> 7, o = el & 127;
    L[dl * 130 + o] = (_Float16)(Wn[el] * 4096.0f);
  }
  __syncthreads();
  _Float16* Wtn = Wt + (size_t)n * 16384 + dq * 32;
  for (int el = tid; el < 4096; el += 256) {
    int o = el >> 5, dl = el & 31;
    Wtn[o * 128 + dl] = L[dl * 130 + o];
  }
}

// ---------------- K0b: fill block-invariant LUTs ----------------
// items: 1280 FFT twiddles | 1025 gather | 513 pack | 512 window  => 3330, 14 blocks
__global__ __launch_bounds__(256) void k_tab(const float* __restrict__ bias) {
  int i = blockIdx.x * 256 + threadIdx.x;
  if (i < 1280) {
    int st = i >> 8, tid = i & 255;
    int s = 2 * st;
    int qm = (tid >> s) << s;   // q * m
    float ang = (float)qm * 6.135923151542565e-3f;   // 2*pi/1024
    d_TW4[st][tid] = make_float4(cosf(ang), sinf(ang), cosf(2.0f * ang), sinf(2.0f * ang));
    d_TW2[st][tid] = make_float2(cosf(3.0f * ang), sinf(3.0f * ang));
  } else if (i < 1280 + 1025) {
    int f = i - 1280;
    int nhi = f / 48; if (nhi > 20) nhi = 20;
    int nlo = (f >= 16) ? (f - 16) / 48 : 0;
    int cnt = nhi - nlo + 1;              // regular-band count (0 only for f==1024)
    int has21 = (f >= 961) ? 1 : 0;
    float bsr = 0.f, bsi = 0.f;
    for (int n = nlo; n <= nhi; n++) {
      bsr += bias[32 * n + 2 * f];
      bsi += bias[32 * n + 2 * f + 1];
    }
    if (has21) { bsr += bias[766 + 2 * f]; bsi += bias[766 + 2 * f + 1]; }
    int wgt = cnt + has21;
    float inv = 1.0f / (float)wgt;
    d_GL[f] = make_float4(0.0f, inv, bsr * inv, bsi * inv);
  } else if (i < 1280 + 1025 + 513) {
    int k = i - 2305;
    float ang = (float)k * 3.0679615757712823e-3f;   // pi/1024
    d_PK[k] = make_float2(cosf(ang), sinf(ang));
  } else if (i < 1280 + 1025 + 513 + 512) {
    int j = i - 2818;   // covers samples 4j..4j+3
    const float inv_n = 1.0f / 2048.0f;
    float4 w;
    w.x = inv_n * 0.5f * (1.0f - cosf((float)(4 * j)     * 3.0679615757712823e-3f));
    w.y = inv_n * 0.5f * (1.0f - cosf((float)(4 * j + 1) * 3.0679615757712823e-3f));
    w.z = inv_n * 0.5f * (1.0f - cosf((float)(4 * j + 2) * 3.0679615757712823e-3f));
    w.w = inv_n * 0.5f * (1.0f - cosf((float)(4 * j + 3) * 3.0679615757712823e-3f));
    d_WN4[j] = w;
  }
}

// ---------------- KA: per-band GEMM, async LDS staging + reg-resident B ----------------
__global__ __launch_bounds__(256) void kA(const float* __restrict__ z,
                                          const _Float16* __restrict__ Wt,
                                          _Float16* __restrict__ band) {
  int mt = blockIdx.x;   // 0..255
  int n  = blockIdx.y;   // 0..21
  int r0 = mt * 64;
  __shared__ __align__(16) char smem[33280];   // 32 row-pairs x 1040B (fp32 z), aliased by epilogue Cs
  int tid = threadIdx.x;
  int lane = tid & 63, wave = tid >> 6;
  int l16 = lane & 15, quad = lane >> 4;

  const _Float16* Wn = Wt + (size_t)n * 16384;
  f16x8 bfrag[8];
#pragma unroll
  for (int kb = 0; kb < 4; kb++) {
    int ko = kb * 32 + quad * 8;
    bfrag[2 * kb]     = *(const f16x8*)(Wn + (wave * 32 + l16) * 128 + ko);
    bfrag[2 * kb + 1] = *(const f16x8*)(Wn + (wave * 32 + 16 + l16) * 128 + ko);
  }

  {
    int col16 = lane & 31;
    int rowh  = lane >> 5;
#pragma unroll
    for (int it = 0; it < 8; it++) {
      int pr = wave * 8 + it;
      const float* g = z + ((size_t)(r0 + 2 * pr + rowh) * 22 + n) * 128 + col16 * 4;
      async_copy16(g, smem + pr * 1040);
    }
  }
  __syncthreads();

  f32x4 acc[2][4];
#pragma unroll
  for (int c = 0; c < 2; c++)
#pragma unroll
    for (int rt = 0; rt < 4; rt++) acc[c][rt] = (f32x4){0.f, 0.f, 0.f, 0.f};

#pragma unroll
  for (int kb = 0; kb < 4; kb++) {
#pragma unroll
    for (int rt = 0; rt < 4; rt++) {
      int row = rt * 16 + l16;
      const float* ap = (const float*)(smem + (row >> 1) * 1040 + (row & 1) * 512) + kb * 32 + quad * 8;
      float4 v0 = *(const float4*)ap;
      float4 v1 = *(const float4*)(ap + 4);
      f16x8 a;
      a[0] = (_Float16)v0.x; a[1] = (_Float16)v0.y; a[2] = (_Float16)v0.z; a[3] = (_Float16)v0.w;
      a[4] = (_Float16)v1.x; a[5] = (_Float16)v1.y; a[6] = (_Float16)v1.z; a[7] = (_Float16)v1.w;
      acc[0][rt] = __builtin_amdgcn_mfma_f32_16x16x32_f16(a, bfrag[2 * kb],     acc[0][rt], 0, 0, 0);
      acc[1][rt] = __builtin_amdgcn_mfma_f32_16x16x32_f16(a, bfrag[2 * kb + 1], acc[1][rt], 0, 0, 0);
    }
  }
  __syncthreads();   // zs dead; reuse smem as Cs staging

  _Float16* Cs = (_Float16*)smem;
  const float inv_scale = 1.0f / 4096.0f;
#pragma unroll
  for (int c = 0; c < 2; c++) {
    int col = (wave * 2 + c) * 16 + l16;
#pragma unroll
    for (int rt = 0; rt < 4; rt++) {
#pragma unroll
      for (int reg = 0; reg < 4; reg++) {
        int row = rt * 16 + quad * 4 + reg;
        Cs[row * 136 + col] = (_Float16)(acc[c][rt][reg] * inv_scale);
      }
    }
  }
  __syncthreads();
  int row = tid >> 2;
  int c4 = (tid & 3) * 32;
  const _Float16* srcl = &Cs[row * 136 + c4];
  _Float16* dst = band + (size_t)(r0 + row) * (SLOT_DW * 2) + n * 128 + c4;
  f16x8 v0 = *(const f16x8*)(srcl);
  f16x8 v1 = *(const f16x8*)(srcl + 8);
  f16x8 v2 = *(const f16x8*)(srcl + 16);
  f16x8 v3 = *(const f16x8*)(srcl + 24);
  *(f16x8*)(dst)      = v0;
  *(f16x8*)(dst + 8)  = v1;
  *(f16x8*)(dst + 16) = v2;
  *(f16x8*)(dst + 24) = v3;
}

// ---------------- KB: mask gather + pack + radix-4 Stockham IFFT + window ----------------
// Gather geometry computed INLINE (band loads issue at top, no LUT->load chain);
// inv/bias from LUT (consumed late). FFT twiddles prefetched one stage ahead.

// GLOAD: compute band addresses arithmetically and issue loads (branchless).
#define GLOAD(S, F) \
  int nhi##S = (F) / 48; if (nhi##S > 20) nhi##S = 20; \
  int nlo##S = ((F) >= 16) ? ((F) - 16) / 48 : 0; \
  int cnt##S = nhi##S - nlo##S + 1; \
  int bas##S = 32 * nlo##S + 2 * (F); \
  f16x2 v0##S = *(const f16x2*)(bandg + bas##S); \
  f16x2 v1##S = *(const f16x2*)(bandg + bas##S + (cnt##S > 1 ? 32 : 0)); \
  f16x2 v2##S = *(const f16x2*)(bandg + (((F) >= 961) ? (766 + 2 * (F)) : bas##S));

// GCOMB: weighted sum + bias + complex multiply with mix.
#define GCOMB(S, F, GE, XR, XI, OR_, OI_) { \
  float c0 = (cnt##S >= 1) ? 1.f : 0.f; \
  float c1 = (cnt##S > 1) ? 1.f : 0.f; \
  float c2 = ((F) >= 961) ? 1.f : 0.f; \
  float sr = c0 * (float)(v0##S[0]) + c1 * (float)(v1##S[0]) + c2 * (float)(v2##S[0]); \
  float si = c0 * (float)(v0##S[1]) + c1 * (float)(v1##S[1]) + c2 * (float)(v2##S[1]); \
  float mr = sr * (GE).y + (GE).z; \
  float mi = si * (GE).y + (GE).w; \
  OR_ = mr * (XR) - mi * (XI); \
  OI_ = mr * (XI) + mi * (XR); }

__global__ __launch_bounds__(256) void kB(const float* __restrict__ mix,
                                          float* __restrict__ ws) {
  int r = blockIdx.x;           // 0..16383
  int b = r >> 11, t = r & 2047;
  __shared__ __align__(16) float2 bufA[1056];   // swizzled: PHYS(i)=i+(i>>5)
  __shared__ __align__(16) float2 bufB[1056];
  int tid = threadIdx.x;

  const _Float16* bandg = (const _Float16*)(ws + (size_t)r * SLOT_DW);
  const float* mixr = mix + ((size_t)(b * 2) * 2048 + t) * 1025;
  const float* mixi = mix + ((size_t)(b * 2 + 1) * 2048 + t) * 1025;

  // f values for the two k-iterations (k=tid, k=tid+256) x two sides, plus k=512
  int f00 = tid, f01 = 1024 - tid, f10 = tid + 256, f11 = 768 - tid;

  // ---- issue ALL latency-bearing loads up front ----
  float4 nw4 = d_TW4[0][tid];            // stage-0 twiddles (prefetch chain start)
  float2 nw2 = d_TW2[0][tid];
  float4 gl00 = d_GL[f00], gl01 = d_GL[f01], gl10 = d_GL[f10], gl11 = d_GL[f11];
  float4 gle  = d_GL[512];               // uniform (broadcast)
  float2 pk0 = d_PK[tid], pk1 = d_PK[tid + 256];
  GLOAD(a, f00) GLOAD(b, f01) GLOAD(c, f10) GLOAD(d, f11) GLOAD(e, 512)
  float xr00 = mixr[f00], xi00 = mixi[f00];
  float xr01 = mixr[f01], xi01 = mixi[f01];
  float xr10 = mixr[f10], xi10 = mixi[f10];
  float xr11 = mixr[f11], xi11 = mixi[f11];
  float xre  = mixr[512], xie  = mixi[512];

  // ---- combine: mask, complex-mul, real-pack ----
  float X00r, X00i, X01r, X01i, X10r, X10i, X11r, X11i, Xer, Xei;
  GCOMB(a, f00, gl00, xr00, xi00, X00r, X00i);
  GCOMB(b, f01, gl01, xr01, xi01, X01r, X01i);
  GCOMB(c, f10, gl10, xr10, xi10, X10r, X10i);
  GCOMB(d, f11, gl11, xr11, xi11, X11r, X11i);
  GCOMB(e, 512, gle,  xre,  xie,  Xer,  Xei);
  if (tid == 0) { X00i = 0.0f; X01i = 0.0f; }   // c2r ignores Im at DC (f=0) / Nyquist (f=1024)

  {  // k = tid
    float Ar = X00r + X01r, Ai = X00i - X01i;
    float Br = X00r - X01r, Bi = X00i + X01i;
    float s1 = pk0.x * Bi + pk0.y * Br;
    float s2 = pk0.x * Br - pk0.y * Bi;
    bufA[PHYS(tid)] = make_float2(Ar - s1, Ai + s2);
    if (tid > 0) bufA[PHYS(1024 - tid)] = make_float2(Ar + s1, -Ai + s2);
  }
  {  // k = tid + 256
    float Ar = X10r + X11r, Ai = X10i - X11i;
    float Br = X10r - X11r, Bi = X10i + X11i;
    float s1 = pk1.x * Bi + pk1.y * Br;
    float s2 = pk1.x * Br - pk1.y * Bi;
    bufA[PHYS(tid + 256)] = make_float2(Ar - s1, Ai + s2);
    bufA[PHYS(768 - tid)] = make_float2(Ar + s1, -Ai + s2);
  }
  // k = 512 (self-paired): X1=X0 => A=(2x,0), B=(0,2y), pk=(0,1) => (2x, -2y)
  if (tid == 0) bufA[PHYS(512)] = make_float2(2.0f * Xer, -2.0f * Xei);

  // ---- radix-4 Stockham inverse FFT (5 double-stages, twiddles prefetched 1 ahead) ----
  float2* src = bufA;
  float2* dst = bufB;
  float4 wn0, wn1;
#pragma unroll
  for (int st = 0; st < 5; st++) {
    const int s = 2 * st;
    const int m = 1 << s;
    float wc1 = nw4.x, ws1 = nw4.y, wc2 = nw4.z, ws2 = nw4.w;
    float wc3 = nw2.x, ws3 = nw2.y;
    if (st < 4) {                       // prefetch next stage's twiddles (hidden under this stage)
      nw4 = d_TW4[st + 1][tid];
      nw2 = d_TW2[st + 1][tid];
    } else {                            // last stage: prefetch window table instead
      wn0 = d_WN4[tid];
      wn1 = d_WN4[tid + 256];
    }
    __syncthreads();
    int q = tid >> s, rr = tid & (m - 1);
    float2 x0 = src[PHYS(tid)];
    float2 x1 = src[PHYS(tid + 256)];
    float2 x2 = src[PHYS(tid + 512)];
    float2 x3 = src[PHYS(tid + 768)];
    float tAr = x0.x + x2.x, tAi = x0.y + x2.y;
    float tBr = x0.x - x2.x, tBi = x0.y - x2.y;
    float tCr = x1.x + x3.x, tCi = x1.y + x3.y;
    float tDr = x1.x - x3.x, tDi = x1.y - x3.y;
    int base = 4 * q * m + rr;
    dst[PHYS(base)] = make_float2(tAr + tCr, tAi + tCi);
    float pr = tBr - tDi, pi = tBi + tDr;                  // tB + i*tD
    dst[PHYS(base + m)] = make_float2(wc1 * pr - ws1 * pi, wc1 * pi + ws1 * pr);
    float qr = tAr - tCr, qi = tAi - tCi;
    dst[PHYS(base + 2 * m)] = make_float2(wc2 * qr - ws2 * qi, wc2 * qi + ws2 * qr);
    float rr2 = tBr + tDi, ri2 = tBi - tDr;                // tB - i*tD
    dst[PHYS(base + 3 * m)] = make_float2(wc3 * rr2 - ws3 * ri2, wc3 * ri2 + ws3 * rr2);
    float2* tmp = src; src = dst; dst = tmp;
  }
  __syncthreads();

  // ---- window + store frame, vectorized: 4 samples / thread / iter ----
  float4* slot4 = (float4*)(ws + (size_t)r * SLOT_DW);
  {
    float2 g0 = src[PHYS(2 * tid)];
    float2 g1 = src[PHYS(2 * tid + 1)];
    slot4[tid] = make_float4(g0.x * wn0.x, g0.y * wn0.y, g1.x * wn0.z, g1.y * wn0.w);
  }
  {
    int i = tid + 256;
    float2 g0 = src[PHYS(2 * i)];
    float2 g1 = src[PHYS(2 * i + 1)];
    slot4[i] = make_float4(g0.x * wn1.x, g0.y * wn1.y, g1.x * wn1.z, g1.y * wn1.w);
  }
}

// ---------------- KC: overlap-add gather + env normalize + crop ----------------
__global__ __launch_bounds__(256) void kC(const float* __restrict__ ws,
                                          float* __restrict__ out) {
  int b = blockIdx.y;
  int p = blockIdx.x * 256 + threadIdx.x;   // 0..1048063 (exact grid)
  int q = p + 1024;
  int t0 = (q - 1536) >> 9; if (t0 < 0) t0 = 0;
  int t1 = q >> 9;          if (t1 > 2047) t1 = 2047;
  float sum = 0.f;
  for (int t = t0; t <= t1; t++) {
    int i = q - (t << 9);
    sum += ws[(size_t)(b * 2048 + t) * SLOT_DW + i];    // frames already windowed
  }
  float env;
  if (t1 - t0 == 3) {
    env = 1.5f;  // Hann, hop=WIN/4: interior sum of win^2 is exactly 1.5
  } else {
    env = 0.f;
    for (int t = t0; t <= t1; t++) {
      int i = q - (t << 9);
      float c = __cosf((float)i * 3.0679615757712823e-3f);
      float win = 0.5f * (1.0f - c);
      env += win * win;
    }
  }
  out[(size_t)b * 1048064 + p] = sum / (env > 1e-11f ? env : 1.0f);
}

extern "C" void kernel_launch(void* const* d_in, const int* in_sizes, int n_in,
                              void* d_out, int out_size, void* d_ws, size_t ws_size,
                              hipStream_t stream) {
  const float* z    = (const float*)d_in[0];
  const float* mix  = (const float*)d_in[1];
  const float* W    = (const float*)d_in[2];
  const float* bias = (const float*)d_in[3];
  float* out = (float*)d_out;
  _Float16* Wt = (_Float16*)((char*)d_ws + WT_BYTE_OFF);

  k_init<<<88, 256, 0, stream>>>(W, Wt);
  k_tab<<<14, 256, 0, stream>>>(bias);
  kA<<<dim3(256, 22), 256, 0, stream>>>(z, Wt, (_Float16*)d_ws);
  kB<<<16384, 256, 0, stream>>>(mix, (float*)d_ws);
  kC<<<dim3(4094, 8), 256, 0, stream>>>((const float*)d_ws, out);
}

// Round 3
// 478.604 us; speedup vs baseline: 1.0853x; 1.0223x over previous
//
#include <hip/hip_runtime.h>

typedef _Float16 f16x8 __attribute__((ext_vector_type(8)));
typedef _Float16 f16x2 __attribute__((ext_vector_type(2)));
typedef float f32x4 __attribute__((ext_vector_type(4)));

#define SLOT_DW 2048              // dwords per (b,t) slot: kA writes 1408 dw (f16 band), kB overwrites with 2048 dw frame
#define WT_BYTE_OFF 134217728     // 16384*2048*4 ; Wt (f16) after slots
#define PHYS(i) ((i) + ((i) >> 5))   // LDS pad swizzle for FFT buffers

// ---- precomputed block-invariant tables (device globals, filled by k_tab) ----
__device__ float4 d_TW4[5][256];   // per (stage, tid): cos/sin of ang, 2*ang  (stage 4 unused: identity)
__device__ float2 d_TW2[5][256];   // per (stage, tid): cos/sin of 3*ang
__device__ float2 d_PK[513];       // pack twiddle: (cos, sin)(k*pi/1024)
__device__ float2 d_WN2[1024];     // window*1/N for samples (2j, 2j+1)
__device__ float4 d_GL[1025];      // gather LUT: (unused, inv, bias_r*inv, bias_i*inv)

__device__ __forceinline__ void async_copy16(const void* g, void* l) {
  __builtin_amdgcn_global_load_lds((const __attribute__((address_space(1))) void*)g,
                                   (__attribute__((address_space(3))) void*)l, 16, 0, 0);
}

// ---------------- K0: transpose+scale W -> Wt[n][o][d] (f16, x4096) ----------------
__global__ __launch_bounds__(256) void k_init(const float* __restrict__ W,
                                              _Float16* __restrict__ Wt) {
  int n = blockIdx.x >> 2, dq = blockIdx.x & 3;
  int tid = threadIdx.x;
  __shared__ _Float16 L[32 * 130];
  const float* Wn = W + (size_t)n * 16384 + dq * 32 * 128;
  for (int el = tid; el < 4096; el += 256) {
    int dl = el >> 7, o = el & 127;
    L[dl * 130 + o] = (_Float16)(Wn[el] * 4096.0f);
  }
  __syncthreads();
  _Float16* Wtn = Wt + (size_t)n * 16384 + dq * 32;
  for (int el = tid; el < 4096; el += 256) {
    int o = el >> 5, dl = el & 31;
    Wtn[o * 128 + dl] = L[dl * 130 + o];
  }
}

// ---------------- K0b: fill block-invariant LUTs ----------------
// items: 1280 FFT twiddles | 1025 gather | 513 pack | 1024 window-pairs => 3842, 16 blocks
__global__ __launch_bounds__(256) void k_tab(const float* __restrict__ bias) {
  int i = blockIdx.x * 256 + threadIdx.x;
  if (i < 1280) {
    int st = i >> 8, tid = i & 255;
    int s = 2 * st;
    int qm = (tid >> s) << s;   // q * m
    float ang = (float)qm * 6.135923151542565e-3f;   // 2*pi/1024
    d_TW4[st][tid] = make_float4(cosf(ang), sinf(ang), cosf(2.0f * ang), sinf(2.0f * ang));
    d_TW2[st][tid] = make_float2(cosf(3.0f * ang), sinf(3.0f * ang));
  } else if (i < 1280 + 1025) {
    int f = i - 1280;
    int nhi = f / 48; if (nhi > 20) nhi = 20;
    int nlo = (f >= 16) ? (f - 16) / 48 : 0;
    int cnt = nhi - nlo + 1;              // regular-band count (0 only for f==1024)
    int has21 = (f >= 961) ? 1 : 0;
    float bsr = 0.f, bsi = 0.f;
    for (int n = nlo; n <= nhi; n++) {
      bsr += bias[32 * n + 2 * f];
      bsi += bias[32 * n + 2 * f + 1];
    }
    if (has21) { bsr += bias[766 + 2 * f]; bsi += bias[766 + 2 * f + 1]; }
    int wgt = cnt + has21;
    float inv = 1.0f / (float)wgt;
    d_GL[f] = make_float4(0.0f, inv, bsr * inv, bsi * inv);
  } else if (i < 1280 + 1025 + 513) {
    int k = i - 2305;
    float ang = (float)k * 3.0679615757712823e-3f;   // pi/1024
    d_PK[k] = make_float2(cosf(ang), sinf(ang));
  } else if (i < 1280 + 1025 + 513 + 1024) {
    int j = i - 2818;   // window pair for samples (2j, 2j+1)
    const float inv_n = 1.0f / 2048.0f;
    float w0 = inv_n * 0.5f * (1.0f - cosf((float)(2 * j)     * 3.0679615757712823e-3f));
    float w1 = inv_n * 0.5f * (1.0f - cosf((float)(2 * j + 1) * 3.0679615757712823e-3f));
    d_WN2[j] = make_float2(w0, w1);
  }
}

// ---------------- KA: per-band GEMM, async LDS staging + reg-resident B ----------------
__global__ __launch_bounds__(256) void kA(const float* __restrict__ z,
                                          const _Float16* __restrict__ Wt,
                                          _Float16* __restrict__ band) {
  int mt = blockIdx.x;   // 0..255
  int n  = blockIdx.y;   // 0..21
  int r0 = mt * 64;
  __shared__ __align__(16) char smem[33280];   // 32 row-pairs x 1040B (fp32 z), aliased by epilogue Cs
  int tid = threadIdx.x;
  int lane = tid & 63, wave = tid >> 6;
  int l16 = lane & 15, quad = lane >> 4;

  const _Float16* Wn = Wt + (size_t)n * 16384;
  f16x8 bfrag[8];
#pragma unroll
  for (int kb = 0; kb < 4; kb++) {
    int ko = kb * 32 + quad * 8;
    bfrag[2 * kb]     = *(const f16x8*)(Wn + (wave * 32 + l16) * 128 + ko);
    bfrag[2 * kb + 1] = *(const f16x8*)(Wn + (wave * 32 + 16 + l16) * 128 + ko);
  }

  {
    int col16 = lane & 31;
    int rowh  = lane >> 5;
#pragma unroll
    for (int it = 0; it < 8; it++) {
      int pr = wave * 8 + it;
      const float* g = z + ((size_t)(r0 + 2 * pr + rowh) * 22 + n) * 128 + col16 * 4;
      async_copy16(g, smem + pr * 1040);
    }
  }
  __syncthreads();

  f32x4 acc[2][4];
#pragma unroll
  for (int c = 0; c < 2; c++)
#pragma unroll
    for (int rt = 0; rt < 4; rt++) acc[c][rt] = (f32x4){0.f, 0.f, 0.f, 0.f};

#pragma unroll
  for (int kb = 0; kb < 4; kb++) {
#pragma unroll
    for (int rt = 0; rt < 4; rt++) {
      int row = rt * 16 + l16;
      const float* ap = (const float*)(smem + (row >> 1) * 1040 + (row & 1) * 512) + kb * 32 + quad * 8;
      float4 v0 = *(const float4*)ap;
      float4 v1 = *(const float4*)(ap + 4);
      f16x8 a;
      a[0] = (_Float16)v0.x; a[1] = (_Float16)v0.y; a[2] = (_Float16)v0.z; a[3] = (_Float16)v0.w;
      a[4] = (_Float16)v1.x; a[5] = (_Float16)v1.y; a[6] = (_Float16)v1.z; a[7] = (_Float16)v1.w;
      acc[0][rt] = __builtin_amdgcn_mfma_f32_16x16x32_f16(a, bfrag[2 * kb],     acc[0][rt], 0, 0, 0);
      acc[1][rt] = __builtin_amdgcn_mfma_f32_16x16x32_f16(a, bfrag[2 * kb + 1], acc[1][rt], 0, 0, 0);
    }
  }
  __syncthreads();   // zs dead; reuse smem as Cs staging

  _Float16* Cs = (_Float16*)smem;
  const float inv_scale = 1.0f / 4096.0f;
#pragma unroll
  for (int c = 0; c < 2; c++) {
    int col = (wave * 2 + c) * 16 + l16;
#pragma unroll
    for (int rt = 0; rt < 4; rt++) {
#pragma unroll
      for (int reg = 0; reg < 4; reg++) {
        int row = rt * 16 + quad * 4 + reg;
        Cs[row * 136 + col] = (_Float16)(acc[c][rt][reg] * inv_scale);
      }
    }
  }
  __syncthreads();
  int row = tid >> 2;
  int c4 = (tid & 3) * 32;
  const _Float16* srcl = &Cs[row * 136 + c4];
  _Float16* dst = band + (size_t)(r0 + row) * (SLOT_DW * 2) + n * 128 + c4;
  f16x8 v0 = *(const f16x8*)(srcl);
  f16x8 v1 = *(const f16x8*)(srcl + 8);
  f16x8 v2 = *(const f16x8*)(srcl + 16);
  f16x8 v3 = *(const f16x8*)(srcl + 24);
  *(f16x8*)(dst)      = v0;
  *(f16x8*)(dst + 8)  = v1;
  *(f16x8*)(dst + 16) = v2;
  *(f16x8*)(dst + 24) = v3;
}

// ---------------- KB: mask gather + pack + radix-4 Stockham IFFT + fused window ----------------
// Gather geometry inline (loads issue at top); inv/bias from LUT. Twiddles prefetched 1 stage
// ahead. Stage 4 has identity twiddles (q=0) -> fused butterfly+window+store in registers.

#define GLOAD(S, F) \
  int nhi##S = (F) / 48; if (nhi##S > 20) nhi##S = 20; \
  int nlo##S = ((F) >= 16) ? ((F) - 16) / 48 : 0; \
  int cnt##S = nhi##S - nlo##S + 1; \
  int bas##S = 32 * nlo##S + 2 * (F); \
  f16x2 v0##S = *(const f16x2*)(bandg + bas##S); \
  f16x2 v1##S = *(const f16x2*)(bandg + bas##S + (cnt##S > 1 ? 32 : 0)); \
  f16x2 v2##S = *(const f16x2*)(bandg + (((F) >= 961) ? (766 + 2 * (F)) : bas##S));

#define GCOMB(S, F, GE, XR, XI, OR_, OI_) { \
  float c0 = (cnt##S >= 1) ? 1.f : 0.f; \
  float c1 = (cnt##S > 1) ? 1.f : 0.f; \
  float c2 = ((F) >= 961) ? 1.f : 0.f; \
  float sr = c0 * (float)(v0##S[0]) + c1 * (float)(v1##S[0]) + c2 * (float)(v2##S[0]); \
  float si = c0 * (float)(v0##S[1]) + c1 * (float)(v1##S[1]) + c2 * (float)(v2##S[1]); \
  float mr = sr * (GE).y + (GE).z; \
  float mi = si * (GE).y + (GE).w; \
  OR_ = mr * (XR) - mi * (XI); \
  OI_ = mr * (XI) + mi * (XR); }

__global__ __launch_bounds__(256) void kB(const float* __restrict__ mix,
                                          float* __restrict__ ws) {
  int r = blockIdx.x;           // 0..16383
  int b = r >> 11, t = r & 2047;
  __shared__ __align__(16) float2 bufA[1056];   // swizzled: PHYS(i)=i+(i>>5)
  __shared__ __align__(16) float2 bufB[1056];
  int tid = threadIdx.x;

  const _Float16* bandg = (const _Float16*)(ws + (size_t)r * SLOT_DW);
  const float* mixr = mix + ((size_t)(b * 2) * 2048 + t) * 1025;
  const float* mixi = mix + ((size_t)(b * 2 + 1) * 2048 + t) * 1025;

  // f values for the two k-iterations (k=tid, k=tid+256) x two sides, plus k=512
  int f00 = tid, f01 = 1024 - tid, f10 = tid + 256, f11 = 768 - tid;

  // ---- issue ALL latency-bearing loads up front ----
  float4 nw4 = d_TW4[0][tid];            // stage-0 twiddles (prefetch chain start)
  float2 nw2 = d_TW2[0][tid];
  float4 gl00 = d_GL[f00], gl01 = d_GL[f01], gl10 = d_GL[f10], gl11 = d_GL[f11];
  float4 gle  = d_GL[512];               // uniform (broadcast)
  float2 pk0 = d_PK[tid], pk1 = d_PK[tid + 256];
  GLOAD(a, f00) GLOAD(b, f01) GLOAD(c, f10) GLOAD(d, f11) GLOAD(e, 512)
  float xr00 = mixr[f00], xi00 = mixi[f00];
  float xr01 = mixr[f01], xi01 = mixi[f01];
  float xr10 = mixr[f10], xi10 = mixi[f10];
  float xr11 = mixr[f11], xi11 = mixi[f11];
  float xre  = mixr[512], xie  = mixi[512];

  // ---- combine: mask, complex-mul, real-pack ----
  float X00r, X00i, X01r, X01i, X10r, X10i, X11r, X11i, Xer, Xei;
  GCOMB(a, f00, gl00, xr00, xi00, X00r, X00i);
  GCOMB(b, f01, gl01, xr01, xi01, X01r, X01i);
  GCOMB(c, f10, gl10, xr10, xi10, X10r, X10i);
  GCOMB(d, f11, gl11, xr11, xi11, X11r, X11i);
  GCOMB(e, 512, gle,  xre,  xie,  Xer,  Xei);
  if (tid == 0) { X00i = 0.0f; X01i = 0.0f; }   // c2r ignores Im at DC (f=0) / Nyquist (f=1024)

  {  // k = tid
    float Ar = X00r + X01r, Ai = X00i - X01i;
    float Br = X00r - X01r, Bi = X00i + X01i;
    float s1 = pk0.x * Bi + pk0.y * Br;
    float s2 = pk0.x * Br - pk0.y * Bi;
    bufA[PHYS(tid)] = make_float2(Ar - s1, Ai + s2);
    if (tid > 0) bufA[PHYS(1024 - tid)] = make_float2(Ar + s1, -Ai + s2);
  }
  {  // k = tid + 256
    float Ar = X10r + X11r, Ai = X10i - X11i;
    float Br = X10r - X11r, Bi = X10i + X11i;
    float s1 = pk1.x * Bi + pk1.y * Br;
    float s2 = pk1.x * Br - pk1.y * Bi;
    bufA[PHYS(tid + 256)] = make_float2(Ar - s1, Ai + s2);
    bufA[PHYS(768 - tid)] = make_float2(Ar + s1, -Ai + s2);
  }
  // k = 512 (self-paired): X1=X0 => A=(2x,0), B=(0,2y), pk=(0,1) => (2x, -2y)
  if (tid == 0) bufA[PHYS(512)] = make_float2(2.0f * Xer, -2.0f * Xei);

  // ---- radix-4 Stockham inverse FFT: stages 0..3 via LDS, twiddles prefetched 1 ahead ----
  float2* src = bufA;
  float2* dst = bufB;
  float2 wnA, wnB, wnC, wnD;
#pragma unroll
  for (int st = 0; st < 4; st++) {
    const int s = 2 * st;
    const int m = 1 << s;
    float wc1 = nw4.x, ws1 = nw4.y, wc2 = nw4.z, ws2 = nw4.w;
    float wc3 = nw2.x, ws3 = nw2.y;
    if (st < 3) {                       // prefetch next stage's twiddles (hidden under this stage)
      nw4 = d_TW4[st + 1][tid];
      nw2 = d_TW2[st + 1][tid];
    } else {                            // last LDS stage: prefetch window pairs for fused stage 4
      wnA = d_WN2[tid];
      wnB = d_WN2[tid + 256];
      wnC = d_WN2[tid + 512];
      wnD = d_WN2[tid + 768];
    }
    __syncthreads();
    int q = tid >> s, rr = tid & (m - 1);
    float2 x0 = src[PHYS(tid)];
    float2 x1 = src[PHYS(tid + 256)];
    float2 x2 = src[PHYS(tid + 512)];
    float2 x3 = src[PHYS(tid + 768)];
    float tAr = x0.x + x2.x, tAi = x0.y + x2.y;
    float tBr = x0.x - x2.x, tBi = x0.y - x2.y;
    float tCr = x1.x + x3.x, tCi = x1.y + x3.y;
    float tDr = x1.x - x3.x, tDi = x1.y - x3.y;
    int base = 4 * q * m + rr;
    dst[PHYS(base)] = make_float2(tAr + tCr, tAi + tCi);
    float pr = tBr - tDi, pi = tBi + tDr;                  // tB + i*tD
    dst[PHYS(base + m)] = make_float2(wc1 * pr - ws1 * pi, wc1 * pi + ws1 * pr);
    float qr = tAr - tCr, qi = tAi - tCi;
    dst[PHYS(base + 2 * m)] = make_float2(wc2 * qr - ws2 * qi, wc2 * qi + ws2 * qr);
    float rr2 = tBr + tDi, ri2 = tBi - tDr;                // tB - i*tD
    dst[PHYS(base + 3 * m)] = make_float2(wc3 * rr2 - ws3 * ri2, wc3 * ri2 + ws3 * rr2);
    float2* tmp = src; src = dst; dst = tmp;
  }
  __syncthreads();

  // ---- stage 4 (m=256, q=0 => identity twiddles) fused with window + store ----
  // outputs land at tid + {0,256,512,768}; frame x[2j]=Re(g[j])*win[2j]/N, x[2j+1]=Im*win[2j+1]/N
  {
    float2 x0 = src[PHYS(tid)];
    float2 x1 = src[PHYS(tid + 256)];
    float2 x2 = src[PHYS(tid + 512)];
    float2 x3 = src[PHYS(tid + 768)];
    float tAr = x0.x + x2.x, tAi = x0.y + x2.y;
    float tBr = x0.x - x2.x, tBi = x0.y - x2.y;
    float tCr = x1.x + x3.x, tCi = x1.y + x3.y;
    float tDr = x1.x - x3.x, tDi = x1.y - x3.y;
    float2* slot2 = (float2*)(ws + (size_t)r * SLOT_DW);
    slot2[tid]       = make_float2((tAr + tCr) * wnA.x, (tAi + tCi) * wnA.y);
    slot2[tid + 256] = make_float2((tBr - tDi) * wnB.x, (tBi + tDr) * wnB.y);
    slot2[tid + 512] = make_float2((tAr - tCr) * wnC.x, (tAi - tCi) * wnC.y);
    slot2[tid + 768] = make_float2((tBr + tDi) * wnD.x, (tBi - tDr) * wnD.y);
  }
}

// ---------------- KC: overlap-add gather + env normalize + crop (4 outputs/thread) ----------------
// Groups of 4 outputs never straddle a hop boundary (512%4==0, q%4==0) -> uniform t0/t1.
__global__ __launch_bounds__(256) void kC(const float* __restrict__ ws,
                                          float* __restrict__ out) {
  int b = blockIdx.y;
  int g = blockIdx.x * 256 + threadIdx.x;   // group of 4 outputs
  if (g >= 262016) return;                  // 1048064 / 4
  int p = g * 4;
  int q = p + 1024;
  int t1 = q >> 9;          if (t1 > 2047) t1 = 2047;
  int t0 = (q - 1536) >> 9; if (t0 < 0) t0 = 0;
  const float* base = ws + (size_t)b * 2048 * SLOT_DW;
  float s0 = 0.f, s1 = 0.f, s2 = 0.f, s3 = 0.f;
  for (int t = t0; t <= t1; t++) {
    int i = q - (t << 9);
    float4 v = *(const float4*)(base + (size_t)t * SLOT_DW + i);   // frames already windowed
    s0 += v.x; s1 += v.y; s2 += v.z; s3 += v.w;
  }
  float4 res;
  if (t1 - t0 == 3) {
    const float inv_env = 0.66666666667f;   // Hann, hop=WIN/4: interior env sum = 1.5
    res = make_float4(s0 * inv_env, s1 * inv_env, s2 * inv_env, s3 * inv_env);
  } else {
    float env[4] = {0.f, 0.f, 0.f, 0.f};
    for (int t = t0; t <= t1; t++) {
      int i0 = q - (t << 9);
#pragma unroll
      for (int e = 0; e < 4; e++) {
        float c = __cosf((float)(i0 + e) * 3.0679615757712823e-3f);
        float w = 0.5f * (1.0f - c);
        env[e] += w * w;
      }
    }
#pragma unroll
    for (int e = 0; e < 4; e++) env[e] = (env[e] > 1e-11f) ? env[e] : 1.0f;
    res = make_float4(s0 / env[0], s1 / env[1], s2 / env[2], s3 / env[3]);
  }
  *(float4*)(out + (size_t)b * 1048064 + p) = res;
}

extern "C" void kernel_launch(void* const* d_in, const int* in_sizes, int n_in,
                              void* d_out, int out_size, void* d_ws, size_t ws_size,
                              hipStream_t stream) {
  const float* z    = (const float*)d_in[0];
  const float* mix  = (const float*)d_in[1];
  const float* W    = (const float*)d_in[2];
  const float* bias = (const float*)d_in[3];
  float* out = (float*)d_out;
  _Float16* Wt = (_Float16*)((char*)d_ws + WT_BYTE_OFF);

  k_init<<<88, 256, 0, stream>>>(W, Wt);
  k_tab<<<16, 256, 0, stream>>>(bias);
  kA<<<dim3(256, 22), 256, 0, stream>>>(z, Wt, (_Float16*)d_ws);
  kB<<<16384, 256, 0, stream>>>(mix, (float*)d_ws);
  kC<<<dim3(1024, 8), 256, 0, stream>>>((const float*)d_ws, out);
}

// Round 4
// 475.481 us; speedup vs baseline: 1.0925x; 1.0066x over previous
//
#include <hip/hip_runtime.h>

typedef _Float16 f16x8 __attribute__((ext_vector_type(8)));
typedef _Float16 f16x2 __attribute__((ext_vector_type(2)));
typedef float f32x4 __attribute__((ext_vector_type(4)));

#define SLOT_DW 2048              // dwords per (b,t) slot: kA writes 1408 dw (f16 band), kB overwrites with 2048 dw frame
#define WT_BYTE_OFF 134217728     // 16384*2048*4 ; Wt (f16) after slots
// XOR bank swizzle for float2 LDS FFT buffers: bits[1:0]^=i[5:4], bits[3:2]^=i[7:6].
// Conflict-free (4 lanes/bank-pair = b64 minimum) for stride-1 reads AND the
// Stockham scatter writes at 4qm+rr+jm for m=1,4,16,64 (verified bitwise).
#define PHYS(i) ((i) ^ (((i) >> 4) & 3) ^ ((((i) >> 6) & 3) << 2))

// ---- precomputed block-invariant tables (device globals, filled by k_init) ----
__device__ float4 d_TW4[5][256];   // per (stage, tid): cos/sin of ang, 2*ang  (stage 4 unused: identity)
__device__ float2 d_TW2[5][256];   // per (stage, tid): cos/sin of 3*ang
__device__ float2 d_PK[513];       // pack twiddle: (cos, sin)(k*pi/1024)
__device__ float2 d_WN2[1024];     // window*1/N for samples (2j, 2j+1)
__device__ float4 d_GL[1025];      // gather LUT: (unused, inv, bias_r*inv, bias_i*inv)

__device__ __forceinline__ void async_copy16(const void* g, void* l) {
  __builtin_amdgcn_global_load_lds((const __attribute__((address_space(1))) void*)g,
                                   (__attribute__((address_space(3))) void*)l, 16, 0, 0);
}

// ---------------- K0: transpose+scale W -> Wt (blocks 0..87) + fill LUTs (blocks 88..103) ----------------
__global__ __launch_bounds__(256) void k_init(const float* __restrict__ W,
                                              _Float16* __restrict__ Wt,
                                              const float* __restrict__ bias) {
  int tid = threadIdx.x;
  if (blockIdx.x < 88) {
    int n = blockIdx.x >> 2, dq = blockIdx.x & 3;
    __shared__ _Float16 L[32 * 130];
    const float* Wn = W + (size_t)n * 16384 + dq * 32 * 128;
    for (int el = tid; el < 4096; el += 256) {
      int dl = el >> 7, o = el & 127;
      L[dl * 130 + o] = (_Float16)(Wn[el] * 4096.0f);
    }
    __syncthreads();
    _Float16* Wtn = Wt + (size_t)n * 16384 + dq * 32;
    for (int el = tid; el < 4096; el += 256) {
      int o = el >> 5, dl = el & 31;
      Wtn[o * 128 + dl] = L[dl * 130 + o];
    }
    return;
  }
  // LUT part: items: 1280 FFT twiddles | 1025 gather | 513 pack | 1024 window-pairs => 3842
  int i = (blockIdx.x - 88) * 256 + tid;
  if (i < 1280) {
    int st = i >> 8, t = i & 255;
    int s = 2 * st;
    int qm = (t >> s) << s;   // q * m
    float ang = (float)qm * 6.135923151542565e-3f;   // 2*pi/1024
    d_TW4[st][t] = make_float4(cosf(ang), sinf(ang), cosf(2.0f * ang), sinf(2.0f * ang));
    d_TW2[st][t] = make_float2(cosf(3.0f * ang), sinf(3.0f * ang));
  } else if (i < 1280 + 1025) {
    int f = i - 1280;
    int nhi = f / 48; if (nhi > 20) nhi = 20;
    int nlo = (f >= 16) ? (f - 16) / 48 : 0;
    int cnt = nhi - nlo + 1;              // regular-band count (0 only for f==1024)
    int has21 = (f >= 961) ? 1 : 0;
    float bsr = 0.f, bsi = 0.f;
    for (int n = nlo; n <= nhi; n++) {
      bsr += bias[32 * n + 2 * f];
      bsi += bias[32 * n + 2 * f + 1];
    }
    if (has21) { bsr += bias[766 + 2 * f]; bsi += bias[766 + 2 * f + 1]; }
    int wgt = cnt + has21;
    float inv = 1.0f / (float)wgt;
    d_GL[f] = make_float4(0.0f, inv, bsr * inv, bsi * inv);
  } else if (i < 1280 + 1025 + 513) {
    int k = i - 2305;
    float ang = (float)k * 3.0679615757712823e-3f;   // pi/1024
    d_PK[k] = make_float2(cosf(ang), sinf(ang));
  } else if (i < 1280 + 1025 + 513 + 1024) {
    int j = i - 2818;   // window pair for samples (2j, 2j+1)
    const float inv_n = 1.0f / 2048.0f;
    float w0 = inv_n * 0.5f * (1.0f - cosf((float)(2 * j)     * 3.0679615757712823e-3f));
    float w1 = inv_n * 0.5f * (1.0f - cosf((float)(2 * j + 1) * 3.0679615757712823e-3f));
    d_WN2[j] = make_float2(w0, w1);
  }
}

// ---------------- KA: per-band GEMM, async LDS staging + reg-resident B ----------------
__global__ __launch_bounds__(256) void kA(const float* __restrict__ z,
                                          const _Float16* __restrict__ Wt,
                                          _Float16* __restrict__ band) {
  int mt = blockIdx.x;   // 0..255
  int n  = blockIdx.y;   // 0..21
  int r0 = mt * 64;
  __shared__ __align__(16) char smem[33280];   // 32 row-pairs x 1040B (fp32 z), aliased by epilogue Cs
  int tid = threadIdx.x;
  int lane = tid & 63, wave = tid >> 6;
  int l16 = lane & 15, quad = lane >> 4;

  const _Float16* Wn = Wt + (size_t)n * 16384;
  f16x8 bfrag[8];
#pragma unroll
  for (int kb = 0; kb < 4; kb++) {
    int ko = kb * 32 + quad * 8;
    bfrag[2 * kb]     = *(const f16x8*)(Wn + (wave * 32 + l16) * 128 + ko);
    bfrag[2 * kb + 1] = *(const f16x8*)(Wn + (wave * 32 + 16 + l16) * 128 + ko);
  }

  {
    int col16 = lane & 31;
    int rowh  = lane >> 5;
#pragma unroll
    for (int it = 0; it < 8; it++) {
      int pr = wave * 8 + it;
      const float* g = z + ((size_t)(r0 + 2 * pr + rowh) * 22 + n) * 128 + col16 * 4;
      async_copy16(g, smem + pr * 1040);
    }
  }
  __syncthreads();

  f32x4 acc[2][4];
#pragma unroll
  for (int c = 0; c < 2; c++)
#pragma unroll
    for (int rt = 0; rt < 4; rt++) acc[c][rt] = (f32x4){0.f, 0.f, 0.f, 0.f};

#pragma unroll
  for (int kb = 0; kb < 4; kb++) {
#pragma unroll
    for (int rt = 0; rt < 4; rt++) {
      int row = rt * 16 + l16;
      const float* ap = (const float*)(smem + (row >> 1) * 1040 + (row & 1) * 512) + kb * 32 + quad * 8;
      float4 v0 = *(const float4*)ap;
      float4 v1 = *(const float4*)(ap + 4);
      f16x8 a;
      a[0] = (_Float16)v0.x; a[1] = (_Float16)v0.y; a[2] = (_Float16)v0.z; a[3] = (_Float16)v0.w;
      a[4] = (_Float16)v1.x; a[5] = (_Float16)v1.y; a[6] = (_Float16)v1.z; a[7] = (_Float16)v1.w;
      acc[0][rt] = __builtin_amdgcn_mfma_f32_16x16x32_f16(a, bfrag[2 * kb],     acc[0][rt], 0, 0, 0);
      acc[1][rt] = __builtin_amdgcn_mfma_f32_16x16x32_f16(a, bfrag[2 * kb + 1], acc[1][rt], 0, 0, 0);
    }
  }
  __syncthreads();   // zs dead; reuse smem as Cs staging

  _Float16* Cs = (_Float16*)smem;
  const float inv_scale = 1.0f / 4096.0f;
#pragma unroll
  for (int c = 0; c < 2; c++) {
    int col = (wave * 2 + c) * 16 + l16;
#pragma unroll
    for (int rt = 0; rt < 4; rt++) {
#pragma unroll
      for (int reg = 0; reg < 4; reg++) {
        int row = rt * 16 + quad * 4 + reg;
        Cs[row * 136 + col] = (_Float16)(acc[c][rt][reg] * inv_scale);
      }
    }
  }
  __syncthreads();
  int row = tid >> 2;
  int c4 = (tid & 3) * 32;
  const _Float16* srcl = &Cs[row * 136 + c4];
  _Float16* dst = band + (size_t)(r0 + row) * (SLOT_DW * 2) + n * 128 + c4;
  f16x8 v0 = *(const f16x8*)(srcl);
  f16x8 v1 = *(const f16x8*)(srcl + 8);
  f16x8 v2 = *(const f16x8*)(srcl + 16);
  f16x8 v3 = *(const f16x8*)(srcl + 24);
  *(f16x8*)(dst)      = v0;
  *(f16x8*)(dst + 8)  = v1;
  *(f16x8*)(dst + 16) = v2;
  *(f16x8*)(dst + 24) = v3;
}

// ---------------- KB: mask gather + pack + radix-4 Stockham IFFT + fused window ----------------
// Gather geometry inline (loads issue at top); inv/bias from LUT. Twiddles prefetched 1 stage
// ahead. Stage 4 has identity twiddles (q=0) -> fused butterfly+window+store in registers.
// LDS buffers use the XOR bank swizzle (conflict-free for all access patterns here).

#define GLOAD(S, F) \
  int nhi##S = (F) / 48; if (nhi##S > 20) nhi##S = 20; \
  int nlo##S = ((F) >= 16) ? ((F) - 16) / 48 : 0; \
  int cnt##S = nhi##S - nlo##S + 1; \
  int bas##S = 32 * nlo##S + 2 * (F); \
  f16x2 v0##S = *(const f16x2*)(bandg + bas##S); \
  f16x2 v1##S = *(const f16x2*)(bandg + bas##S + (cnt##S > 1 ? 32 : 0)); \
  f16x2 v2##S = *(const f16x2*)(bandg + (((F) >= 961) ? (766 + 2 * (F)) : bas##S));

#define GCOMB(S, F, GE, XR, XI, OR_, OI_) { \
  float c0 = (cnt##S >= 1) ? 1.f : 0.f; \
  float c1 = (cnt##S > 1) ? 1.f : 0.f; \
  float c2 = ((F) >= 961) ? 1.f : 0.f; \
  float sr = c0 * (float)(v0##S[0]) + c1 * (float)(v1##S[0]) + c2 * (float)(v2##S[0]); \
  float si = c0 * (float)(v0##S[1]) + c1 * (float)(v1##S[1]) + c2 * (float)(v2##S[1]); \
  float mr = sr * (GE).y + (GE).z; \
  float mi = si * (GE).y + (GE).w; \
  OR_ = mr * (XR) - mi * (XI); \
  OI_ = mr * (XI) + mi * (XR); }

__global__ __launch_bounds__(256) void kB(const float* __restrict__ mix,
                                          float* __restrict__ ws) {
  int r = blockIdx.x;           // 0..16383
  int b = r >> 11, t = r & 2047;
  __shared__ __align__(16) float2 bufA[1024];   // XOR-swizzled via PHYS
  __shared__ __align__(16) float2 bufB[1024];
  int tid = threadIdx.x;

  const _Float16* bandg = (const _Float16*)(ws + (size_t)r * SLOT_DW);
  const float* mixr = mix + ((size_t)(b * 2) * 2048 + t) * 1025;
  const float* mixi = mix + ((size_t)(b * 2 + 1) * 2048 + t) * 1025;

  // f values for the two k-iterations (k=tid, k=tid+256) x two sides, plus k=512
  int f00 = tid, f01 = 1024 - tid, f10 = tid + 256, f11 = 768 - tid;

  // ---- issue ALL latency-bearing loads up front ----
  float4 nw4 = d_TW4[0][tid];            // stage-0 twiddles (prefetch chain start)
  float2 nw2 = d_TW2[0][tid];
  float4 gl00 = d_GL[f00], gl01 = d_GL[f01], gl10 = d_GL[f10], gl11 = d_GL[f11];
  float4 gle  = d_GL[512];               // uniform (broadcast)
  float2 pk0 = d_PK[tid], pk1 = d_PK[tid + 256];
  GLOAD(a, f00) GLOAD(b, f01) GLOAD(c, f10) GLOAD(d, f11) GLOAD(e, 512)
  float xr00 = mixr[f00], xi00 = mixi[f00];
  float xr01 = mixr[f01], xi01 = mixi[f01];
  float xr10 = mixr[f10], xi10 = mixi[f10];
  float xr11 = mixr[f11], xi11 = mixi[f11];
  float xre  = mixr[512], xie  = mixi[512];

  // ---- combine: mask, complex-mul, real-pack ----
  float X00r, X00i, X01r, X01i, X10r, X10i, X11r, X11i, Xer, Xei;
  GCOMB(a, f00, gl00, xr00, xi00, X00r, X00i);
  GCOMB(b, f01, gl01, xr01, xi01, X01r, X01i);
  GCOMB(c, f10, gl10, xr10, xi10, X10r, X10i);
  GCOMB(d, f11, gl11, xr11, xi11, X11r, X11i);
  GCOMB(e, 512, gle,  xre,  xie,  Xer,  Xei);
  if (tid == 0) { X00i = 0.0f; X01i = 0.0f; }   // c2r ignores Im at DC (f=0) / Nyquist (f=1024)

  {  // k = tid
    float Ar = X00r + X01r, Ai = X00i - X01i;
    float Br = X00r - X01r, Bi = X00i + X01i;
    float s1 = pk0.x * Bi + pk0.y * Br;
    float s2 = pk0.x * Br - pk0.y * Bi;
    bufA[PHYS(tid)] = make_float2(Ar - s1, Ai + s2);
    if (tid > 0) bufA[PHYS(1024 - tid)] = make_float2(Ar + s1, -Ai + s2);
  }
  {  // k = tid + 256
    float Ar = X10r + X11r, Ai = X10i - X11i;
    float Br = X10r - X11r, Bi = X10i + X11i;
    float s1 = pk1.x * Bi + pk1.y * Br;
    float s2 = pk1.x * Br - pk1.y * Bi;
    bufA[PHYS(tid + 256)] = make_float2(Ar - s1, Ai + s2);
    bufA[PHYS(768 - tid)] = make_float2(Ar + s1, -Ai + s2);
  }
  // k = 512 (self-paired): X1=X0 => A=(2x,0), B=(0,2y), pk=(0,1) => (2x, -2y)
  if (tid == 0) bufA[PHYS(512)] = make_float2(2.0f * Xer, -2.0f * Xei);

  // ---- radix-4 Stockham inverse FFT: stages 0..3 via LDS, twiddles prefetched 1 ahead ----
  float2* src = bufA;
  float2* dst = bufB;
  float2 wnA, wnB, wnC, wnD;
#pragma unroll
  for (int st = 0; st < 4; st++) {
    const int s = 2 * st;
    const int m = 1 << s;
    float wc1 = nw4.x, ws1 = nw4.y, wc2 = nw4.z, ws2 = nw4.w;
    float wc3 = nw2.x, ws3 = nw2.y;
    if (st < 3) {                       // prefetch next stage's twiddles (hidden under this stage)
      nw4 = d_TW4[st + 1][tid];
      nw2 = d_TW2[st + 1][tid];
    } else {                            // last LDS stage: prefetch window pairs for fused stage 4
      wnA = d_WN2[tid];
      wnB = d_WN2[tid + 256];
      wnC = d_WN2[tid + 512];
      wnD = d_WN2[tid + 768];
    }
    __syncthreads();
    int q = tid >> s, rr = tid & (m - 1);
    float2 x0 = src[PHYS(tid)];
    float2 x1 = src[PHYS(tid + 256)];
    float2 x2 = src[PHYS(tid + 512)];
    float2 x3 = src[PHYS(tid + 768)];
    float tAr = x0.x + x2.x, tAi = x0.y + x2.y;
    float tBr = x0.x - x2.x, tBi = x0.y - x2.y;
    float tCr = x1.x + x3.x, tCi = x1.y + x3.y;
    float tDr = x1.x - x3.x, tDi = x1.y - x3.y;
    int base = 4 * q * m + rr;
    dst[PHYS(base)] = make_float2(tAr + tCr, tAi + tCi);
    float pr = tBr - tDi, pi = tBi + tDr;                  // tB + i*tD
    dst[PHYS(base + m)] = make_float2(wc1 * pr - ws1 * pi, wc1 * pi + ws1 * pr);
    float qr = tAr - tCr, qi = tAi - tCi;
    dst[PHYS(base + 2 * m)] = make_float2(wc2 * qr - ws2 * qi, wc2 * qi + ws2 * qr);
    float rr2 = tBr + tDi, ri2 = tBi - tDr;                // tB - i*tD
    dst[PHYS(base + 3 * m)] = make_float2(wc3 * rr2 - ws3 * ri2, wc3 * ri2 + ws3 * rr2);
    float2* tmp = src; src = dst; dst = tmp;
  }
  __syncthreads();

  // ---- stage 4 (m=256, q=0 => identity twiddles) fused with window + store ----
  {
    float2 x0 = src[PHYS(tid)];
    float2 x1 = src[PHYS(tid + 256)];
    float2 x2 = src[PHYS(tid + 512)];
    float2 x3 = src[PHYS(tid + 768)];
    float tAr = x0.x + x2.x, tAi = x0.y + x2.y;
    float tBr = x0.x - x2.x, tBi = x0.y - x2.y;
    float tCr = x1.x + x3.x, tCi = x1.y + x3.y;
    float tDr = x1.x - x3.x, tDi = x1.y - x3.y;
    float2* slot2 = (float2*)(ws + (size_t)r * SLOT_DW);
    slot2[tid]       = make_float2((tAr + tCr) * wnA.x, (tAi + tCi) * wnA.y);
    slot2[tid + 256] = make_float2((tBr - tDi) * wnB.x, (tBi + tDr) * wnB.y);
    slot2[tid + 512] = make_float2((tAr - tCr) * wnC.x, (tAi - tCi) * wnC.y);
    slot2[tid + 768] = make_float2((tBr + tDi) * wnD.x, (tBi - tDr) * wnD.y);
  }
}

// ---------------- KC: overlap-add gather + env normalize + crop (8 outputs/thread) ----------------
// Groups of 8 never straddle a hop boundary (512%8==0, q%8==0) -> uniform t0/t1; and
// i = q-512t with q%8==0 gives i <= 2040, so i..i+7 stays inside the 2048-sample frame.
__global__ __launch_bounds__(256) void kC(const float* __restrict__ ws,
                                          float* __restrict__ out) {
  int b = blockIdx.y;
  int g = blockIdx.x * 256 + threadIdx.x;   // group of 8 outputs
  if (g >= 131008) return;                  // 1048064 / 8
  int p = g * 8;
  int q = p + 1024;
  int t1 = q >> 9;          if (t1 > 2047) t1 = 2047;
  int t0 = (q - 1536) >> 9; if (t0 < 0) t0 = 0;
  const float* base = ws + (size_t)b * 2048 * SLOT_DW;
  float s[8] = {0.f, 0.f, 0.f, 0.f, 0.f, 0.f, 0.f, 0.f};
  if (t1 - t0 == 3) {
    // interior: exactly 4 frames, env sum = 1.5
#pragma unroll
    for (int e = 0; e < 4; e++) {
      int tt = t0 + e;
      int i = q - (tt << 9);
      const float* fp = base + (size_t)tt * SLOT_DW + i;
      float4 va = *(const float4*)(fp);
      float4 vb = *(const float4*)(fp + 4);
      s[0] += va.x; s[1] += va.y; s[2] += va.z; s[3] += va.w;
      s[4] += vb.x; s[5] += vb.y; s[6] += vb.z; s[7] += vb.w;
    }
    const float inv_env = 0.66666666667f;
    float4 r0 = make_float4(s[0] * inv_env, s[1] * inv_env, s[2] * inv_env, s[3] * inv_env);
    float4 r1 = make_float4(s[4] * inv_env, s[5] * inv_env, s[6] * inv_env, s[7] * inv_env);
    float* op = out + (size_t)b * 1048064 + p;
    *(float4*)(op)     = r0;
    *(float4*)(op + 4) = r1;
  } else {
    float env[8] = {0.f, 0.f, 0.f, 0.f, 0.f, 0.f, 0.f, 0.f};
    for (int tt = t0; tt <= t1; tt++) {
      int i = q - (tt << 9);
      const float* fp = base + (size_t)tt * SLOT_DW + i;
      float4 va = *(const float4*)(fp);
      float4 vb = *(const float4*)(fp + 4);
      s[0] += va.x; s[1] += va.y; s[2] += va.z; s[3] += va.w;
      s[4] += vb.x; s[5] += vb.y; s[6] += vb.z; s[7] += vb.w;
#pragma unroll
      for (int e = 0; e < 8; e++) {
        float c = __cosf((float)(i + e) * 3.0679615757712823e-3f);
        float w = 0.5f * (1.0f - c);
        env[e] += w * w;
      }
    }
    float* op = out + (size_t)b * 1048064 + p;
#pragma unroll
    for (int e = 0; e < 8; e++) {
      float ev = (env[e] > 1e-11f) ? env[e] : 1.0f;
      op[e] = s[e] / ev;
    }
  }
}

extern "C" void kernel_launch(void* const* d_in, const int* in_sizes, int n_in,
                              void* d_out, int out_size, void* d_ws, size_t ws_size,
                              hipStream_t stream) {
  const float* z    = (const float*)d_in[0];
  const float* mix  = (const float*)d_in[1];
  const float* W    = (const float*)d_in[2];
  const float* bias = (const float*)d_in[3];
  float* out = (float*)d_out;
  _Float16* Wt = (_Float16*)((char*)d_ws + WT_BYTE_OFF);

  k_init<<<104, 256, 0, stream>>>(W, Wt, bias);
  kA<<<dim3(256, 22), 256, 0, stream>>>(z, Wt, (_Float16*)d_ws);
  kB<<<16384, 256, 0, stream>>>(mix, (float*)d_ws);
  kC<<<dim3(512, 8), 256, 0, stream>>>((const float*)d_ws, out);
}